// Round 9
// baseline (2671.793 us; speedup 1.0000x reference)
//
#include <hip/hip_runtime.h>
#include <stdint.h>

typedef unsigned short u16;
typedef unsigned int u32;
typedef __bf16 bf16x8 __attribute__((ext_vector_type(8)));
typedef __bf16 bf16x4 __attribute__((ext_vector_type(4)));
typedef float f32x4 __attribute__((ext_vector_type(4)));

// ---------- helpers ----------
__device__ __forceinline__ u16 f2bf(float f) {
  u32 u = __builtin_bit_cast(u32, f);
  u32 r = (u + 0x7FFFu + ((u >> 16) & 1u)) >> 16;
  return (u16)r;
}

// ---------- weight fp32 -> bf16 (one layer: wq,wk,wv,wo,w1,w2 packed) ----------
__global__ __launch_bounds__(256)
void convert_w(const float* __restrict__ wq, const float* __restrict__ wk,
               const float* __restrict__ wv, const float* __restrict__ wo,
               const float* __restrict__ w1, const float* __restrict__ w2,
               u16* __restrict__ out) {
  size_t i = ((size_t)blockIdx.x * 256 + threadIdx.x) * 4;
  if (i >= 5505024) return;
  const float* src; size_t off;
  if (i < 589824)       { src = wq; off = i; }
  else if (i < 1179648) { src = wk; off = i - 589824; }
  else if (i < 1769472) { src = wv; off = i - 1179648; }
  else if (i < 2359296) { src = wo; off = i - 1769472; }
  else if (i < 3932160) { src = w1; off = i - 2359296; }
  else                  { src = w2; off = i - 3932160; }
  float4 v = *(const float4*)(src + off);
  u32 lo = (u32)f2bf(v.x) | ((u32)f2bf(v.y) << 16);
  u32 hi = (u32)f2bf(v.z) | ((u32)f2bf(v.w) << 16);
  *(uint2*)(out + i) = make_uint2(lo, hi);
}

// ---------- RMSNorm fp32 -> bf16 (D=768), one wave per token ----------
__device__ __forceinline__ void rn_store4(u16* p, float4 v, float4 w, float sc) {
  u32 lo = (u32)f2bf(v.x * sc * w.x) | ((u32)f2bf(v.y * sc * w.y) << 16);
  u32 hi = (u32)f2bf(v.z * sc * w.z) | ((u32)f2bf(v.w * sc * w.w) << 16);
  *(uint2*)p = make_uint2(lo, hi);
}

__global__ __launch_bounds__(256)
void rmsnorm_k(const float* __restrict__ x, const float* __restrict__ w,
               u16* __restrict__ out) {
  const int tok = (blockIdx.x << 2) + (threadIdx.x >> 6);
  const int l = threadIdx.x & 63;
  const float* xr = x + (size_t)tok * 768;
  float4 v0 = *(const float4*)(xr + l * 4);
  float4 v1 = *(const float4*)(xr + 256 + l * 4);
  float4 v2 = *(const float4*)(xr + 512 + l * 4);
  float ss = v0.x*v0.x + v0.y*v0.y + v0.z*v0.z + v0.w*v0.w
           + v1.x*v1.x + v1.y*v1.y + v1.z*v1.z + v1.w*v1.w
           + v2.x*v2.x + v2.y*v2.y + v2.z*v2.z + v2.w*v2.w;
  ss += __shfl_xor(ss, 1);  ss += __shfl_xor(ss, 2);  ss += __shfl_xor(ss, 4);
  ss += __shfl_xor(ss, 8);  ss += __shfl_xor(ss, 16); ss += __shfl_xor(ss, 32);
  float sc = rsqrtf(ss * (1.f / 768.f) + 1e-12f);
  float4 w0 = *(const float4*)(w + l * 4);
  float4 w1v = *(const float4*)(w + 256 + l * 4);
  float4 w2v = *(const float4*)(w + 512 + l * 4);
  u16* o = out + (size_t)tok * 768;
  rn_store4(o + l * 4, v0, w0, sc);
  rn_store4(o + 256 + l * 4, v1, w1v, sc);
  rn_store4(o + 512 + l * 4, v2, w2v, sc);
}

// ---------- GEMM core staging+compute (128x128 tile, 4 waves, m97 structure) ----------
#define GEMM_CORE(A_, W_, K_, m0_, n0_)                                             \
  for (int kt = 0; kt < (K_); kt += 64) {                                           \
    __syncthreads();                                                                \
    _Pragma("unroll")                                                               \
    for (int ii = 0; ii < 4; ++ii) {                                                \
      int issue = (w << 2) + ii;                                                    \
      int r = (issue << 3) + (l >> 3);                                              \
      int c = (l & 7) ^ (r & 7);                                                    \
      __builtin_amdgcn_global_load_lds((A_) + (size_t)((m0_) + r) * (K_) + kt + c * 8, \
                                       As + issue * 512, 16, 0, 0);                 \
      __builtin_amdgcn_global_load_lds((W_) + (size_t)((n0_) + r) * (K_) + kt + c * 8, \
                                       Ws + issue * 512, 16, 0, 0);                 \
    }                                                                               \
    __syncthreads();                                                                \
    _Pragma("unroll")                                                               \
    for (int kc = 0; kc < 2; ++kc) {                                                \
      int chunk = lg + (kc << 2);                                                   \
      bf16x8 af[4], bfr[4];                                                         \
      _Pragma("unroll")                                                             \
      for (int i = 0; i < 4; ++i) {                                                 \
        int mr = (wm << 6) + (i << 4) + ll;                                         \
        af[i] = *(const bf16x8*)((const char*)As + mr * 128 + ((chunk ^ (mr & 7)) << 4)); \
        int nr = (wn << 6) + (i << 4) + ll;                                         \
        bfr[i] = *(const bf16x8*)((const char*)Ws + nr * 128 + ((chunk ^ (nr & 7)) << 4)); \
      }                                                                             \
      _Pragma("unroll")                                                             \
      for (int i = 0; i < 4; ++i)                                                   \
        _Pragma("unroll")                                                           \
        for (int j = 0; j < 4; ++j)                                                 \
          acc[i][j] = __builtin_amdgcn_mfma_f32_16x16x32_bf16(af[i], bfr[j], acc[i][j], 0, 0, 0); \
    }                                                                               \
  }

// ---------- generic BT GEMM (kept for qkv path compatibility) ----------
template<int EP>
__global__ __launch_bounds__(256, 2)
void gemm_bt(const u16* __restrict__ A, const u16* __restrict__ W,
             void* __restrict__ outp, const float* __restrict__ Res,
             int M, int N, int K) {
  __shared__ __align__(16) u16 As[128 * 64];
  __shared__ __align__(16) u16 Ws[128 * 64];
  const int tid = threadIdx.x;
  const int w = tid >> 6, l = tid & 63;
  const int lg = l >> 4, ll = l & 15;
  const int ntiles = N >> 7;
  const int mt = blockIdx.x / ntiles, nt = blockIdx.x - mt * ntiles;
  const int m0 = mt << 7, n0 = nt << 7;
  const int wm = w >> 1, wn = w & 1;

  const f32x4 fz = {0.f, 0.f, 0.f, 0.f};
  f32x4 acc[4][4];
#pragma unroll
  for (int i = 0; i < 4; ++i)
#pragma unroll
    for (int j = 0; j < 4; ++j) acc[i][j] = fz;

  GEMM_CORE(A, W, K, m0, n0)

  const int g4 = lg << 2;
#pragma unroll
  for (int i = 0; i < 4; ++i) {
#pragma unroll
    for (int j = 0; j < 4; ++j) {
      int row0 = m0 + (wm << 6) + (i << 4) + g4;
      int col = n0 + (wn << 6) + (j << 4) + ll;
      f32x4 v = acc[i][j];
      if (EP == 0) {
        u16* o = (u16*)outp;
#pragma unroll
        for (int e = 0; e < 4; ++e) o[(size_t)(row0 + e) * N + col] = f2bf(v[e]);
      } else if (EP == 1) {
        float* o = (float*)outp;
#pragma unroll
        for (int e = 0; e < 4; ++e) {
          size_t idx = (size_t)(row0 + e) * N + col;
          o[idx] = Res[idx] + v[e];
        }
      } else {
        u16* o = (u16*)outp;
#pragma unroll
        for (int e = 0; e < 4; ++e) {
          float xx = v[e];
          o[(size_t)(row0 + e) * N + col] = f2bf(xx / (1.f + __expf(-xx)));
        }
      }
    }
  }
}

// ---------- 64x128-tile BT GEMM, fp32-residual epilogue (wo / ffn2) ----------
__global__ __launch_bounds__(256, 4)
void gemm_bt64(const u16* __restrict__ A, const u16* __restrict__ W,
               float* __restrict__ outp, const float* __restrict__ Res,
               int M, int N, int K) {
  __shared__ __align__(16) u16 As[64 * 64];
  __shared__ __align__(16) u16 Ws[128 * 64];
  const int tid = threadIdx.x;
  const int w = tid >> 6, l = tid & 63;
  const int lg = l >> 4, ll = l & 15;
  const int ntiles = N >> 7;
  const int mt = blockIdx.x / ntiles, nt = blockIdx.x - mt * ntiles;
  const int m0 = mt << 6, n0 = nt << 7;
  const int wm = w >> 1, wn = w & 1;

  const f32x4 fz = {0.f, 0.f, 0.f, 0.f};
  f32x4 acc[2][4];
#pragma unroll
  for (int i = 0; i < 2; ++i)
#pragma unroll
    for (int j = 0; j < 4; ++j) acc[i][j] = fz;

  for (int kt = 0; kt < K; kt += 64) {
    __syncthreads();
#pragma unroll
    for (int ii = 0; ii < 6; ++ii) {
      int issue = w * 6 + ii;  // 0..23, wave-uniform
      if (issue < 8) {
        int r = (issue << 3) + (l >> 3);
        int c = (l & 7) ^ (r & 7);
        __builtin_amdgcn_global_load_lds(A + (size_t)(m0 + r) * K + kt + c * 8,
                                         As + issue * 512, 16, 0, 0);
      } else {
        int is2 = issue - 8;
        int r = (is2 << 3) + (l >> 3);
        int c = (l & 7) ^ (r & 7);
        __builtin_amdgcn_global_load_lds(W + (size_t)(n0 + r) * K + kt + c * 8,
                                         Ws + is2 * 512, 16, 0, 0);
      }
    }
    __syncthreads();
#pragma unroll
    for (int kc = 0; kc < 2; ++kc) {
      int chunk = lg + (kc << 2);
      bf16x8 af[2], bfr[4];
#pragma unroll
      for (int i = 0; i < 2; ++i) {
        int mr = (wm << 5) + (i << 4) + ll;
        af[i] = *(const bf16x8*)((const char*)As + mr * 128 + ((chunk ^ (mr & 7)) << 4));
      }
#pragma unroll
      for (int j = 0; j < 4; ++j) {
        int nr = (wn << 6) + (j << 4) + ll;
        bfr[j] = *(const bf16x8*)((const char*)Ws + nr * 128 + ((chunk ^ (nr & 7)) << 4));
      }
#pragma unroll
      for (int i = 0; i < 2; ++i)
#pragma unroll
        for (int j = 0; j < 4; ++j)
          acc[i][j] = __builtin_amdgcn_mfma_f32_16x16x32_bf16(af[i], bfr[j], acc[i][j], 0, 0, 0);
    }
  }

  const int g4 = lg << 2;
#pragma unroll
  for (int i = 0; i < 2; ++i) {
#pragma unroll
    for (int j = 0; j < 4; ++j) {
      int row0 = m0 + (wm << 5) + (i << 4) + g4;
      int col = n0 + (wn << 6) + (j << 4) + ll;
      f32x4 v = acc[i][j];
#pragma unroll
      for (int e = 0; e < 4; ++e) {
        size_t idx = (size_t)(row0 + e) * N + col;
        outp[idx] = Res[idx] + v[e];
      }
    }
  }
}

// ---------- fused QKV GEMM: A[8192][768] x Wqkv[2304][768]; routes per n-tile ----------
__global__ __launch_bounds__(256, 2)
void gemm_qkv(const u16* __restrict__ A, const u16* __restrict__ W,
              u16* __restrict__ Qo, u16* __restrict__ Ko, u16* __restrict__ Vo) {
  __shared__ __align__(16) u16 As[128 * 64];
  __shared__ __align__(16) u16 Ws[128 * 64];
  const int tid = threadIdx.x;
  const int w = tid >> 6, l = tid & 63;
  const int lg = l >> 4, ll = l & 15;
  const int mt = blockIdx.x / 18, nt = blockIdx.x - mt * 18;
  const int m0 = mt << 7, n0 = nt << 7;
  const int wm = w >> 1, wn = w & 1;
  const int K = 768;

  const f32x4 fz = {0.f, 0.f, 0.f, 0.f};
  f32x4 acc[4][4];
#pragma unroll
  for (int i = 0; i < 4; ++i)
#pragma unroll
    for (int j = 0; j < 4; ++j) acc[i][j] = fz;

  GEMM_CORE(A, W, K, m0, n0)

  const int g4 = lg << 2;
#pragma unroll
  for (int i = 0; i < 4; ++i) {
#pragma unroll
    for (int j = 0; j < 4; ++j) {
      int row0 = m0 + (wm << 6) + (i << 4) + g4;
      int col = n0 + (wn << 6) + (j << 4) + ll;
      f32x4 v = acc[i][j];
      if (nt < 12) {
        u16* o = (nt < 6) ? Qo : Ko;
        int c = (nt < 6) ? col : (col - 768);
#pragma unroll
        for (int e = 0; e < 4; ++e) o[(size_t)(row0 + e) * 768 + c] = f2bf(v[e]);
      } else {
        int c = col - 1536;
        int vrow = ((row0 >> 10) * 768) + c;
        u32 lo = (u32)f2bf(v[0]) | ((u32)f2bf(v[1]) << 16);
        u32 hi = (u32)f2bf(v[2]) | ((u32)f2bf(v[3]) << 16);
        *(uint2*)(Vo + ((size_t)vrow << 10) + (row0 & 1023)) = make_uint2(lo, hi);
      }
    }
  }
}

// ---------- 256x256-tile 8-phase pipelined GEMM, silu epilogue (ffn1) ----------
// 512 thr / 8 waves (2M x 4N). BK=64 split into 2 k-halves. LDS = 8 half-slots
// (A/B x khalf x parity, 16KB each = 128KB). Per K-tile: 4 phases, each stages one
// half-tile of a future K-tile; raw s_barrier + counted s_waitcnt vmcnt(4) at P4
// only (leaves the 2 newest halves in flight across barriers - T3+T4).
// Stage schedule (derived so every read is covered by the previous P4 vmcnt):
//   P1: stage B.k1(t+1)   P2: stage A.k1(t+1)   P3: stage B.k0(t+2)   P4: stage A.k0(t+2)
// Slot swizzle: LDS[row][cc] = global[row][cc ^ ((row>>1)&3)] (16B chunks) -> 2-way
// bank aliasing on ds_read_b128 (free, m136); gload_lds dest linear (rule #21).
__global__ __launch_bounds__(512, 2)
void gemm256_silu(const u16* __restrict__ A, const u16* __restrict__ W,
                  u16* __restrict__ out, int M, int N, int K) {
  // slots: 0/1 = A.k0 par0/1, 2/3 = A.k1, 4/5 = B.k0, 6/7 = B.k1
  __shared__ __align__(16) u16 LDS[8][8192];
  const int tid = threadIdx.x;
  const int w = tid >> 6, l = tid & 63;
  const int lg = l >> 4, ll = l & 15;
  const int wm = w >> 2, wn = w & 3;
  const int ntiles = N >> 8;
  const int mt = blockIdx.x / ntiles, nt = blockIdx.x - mt * ntiles;
  const int m0 = mt << 8, n0 = nt << 8;
  const int T = K >> 6;

  const f32x4 fz = {0.f, 0.f, 0.f, 0.f};
  f32x4 acc[8][4];
#pragma unroll
  for (int i = 0; i < 8; ++i)
#pragma unroll
    for (int j = 0; j < 4; ++j) acc[i][j] = fz;

  // stage one half-tile (256 rows x 32 kcols) into slot s
#define STG(gb, rows0, t_, kh, s)                                                    \
  { _Pragma("unroll")                                                                \
    for (int rr = 0; rr < 256; rr += 128) {                                          \
      int rl = rr + (tid >> 2);                                                      \
      int cc = (tid & 3) ^ ((rl >> 1) & 3);                                          \
      __builtin_amdgcn_global_load_lds(                                              \
          (gb) + (size_t)((rows0) + rl) * K + ((t_) << 6) + ((kh) << 5) + (cc << 3), \
          &LDS[s][(rr + (w << 4)) * 32], 16, 0, 0);                                  \
    } }
#define BARR __builtin_amdgcn_s_barrier()
#define VMW asm volatile("s_waitcnt vmcnt(4)" ::: "memory")

  auto lda = [&](int s, int i) -> bf16x8 {
    int r = (wm << 7) + (i << 4) + ll;
    return *(const bf16x8*)((const char*)&LDS[s][0] + r * 64 + ((lg ^ ((r >> 1) & 3)) << 4));
  };
  auto ldb = [&](int s, int j) -> bf16x8 {
    int r = (wn << 6) + (j << 4) + ll;
    return *(const bf16x8*)((const char*)&LDS[s][0] + r * 64 + ((lg ^ ((r >> 1) & 3)) << 4));
  };

  // prologue: B.k0(0), A.k0(0), B.k1(0), A.k1(0), B.k0(1), A.k0(1)
  STG(W, n0, 0, 0, 4); STG(A, m0, 0, 0, 0);
  STG(W, n0, 0, 1, 6); STG(A, m0, 0, 1, 2);
  STG(W, n0, 1, 0, 5); STG(A, m0, 1, 0, 1);
  VMW; BARR;

  for (int t = 0; t < T; ++t) {
    const int par = t & 1, npar = par ^ 1;
    bf16x8 af[4], bfr[4];
    // P1: kc0, m-frags 0-3 (+ load B.k0 frags)
#pragma unroll
    for (int i = 0; i < 4; ++i) af[i] = lda(0 + par, i);
#pragma unroll
    for (int j = 0; j < 4; ++j) bfr[j] = ldb(4 + par, j);
    if (t + 1 < T) STG(W, n0, t + 1, 1, 6 + npar);
    BARR; __builtin_amdgcn_s_setprio(1);
#pragma unroll
    for (int i = 0; i < 4; ++i)
#pragma unroll
      for (int j = 0; j < 4; ++j)
        acc[i][j] = __builtin_amdgcn_mfma_f32_16x16x32_bf16(af[i], bfr[j], acc[i][j], 0, 0, 0);
    __builtin_amdgcn_s_setprio(0); BARR;
    // P2: kc0, m-frags 4-7 (B reused from registers)
#pragma unroll
    for (int i = 0; i < 4; ++i) af[i] = lda(0 + par, 4 + i);
    if (t + 1 < T) STG(A, m0, t + 1, 1, 2 + npar);
    BARR; __builtin_amdgcn_s_setprio(1);
#pragma unroll
    for (int i = 0; i < 4; ++i)
#pragma unroll
      for (int j = 0; j < 4; ++j)
        acc[4 + i][j] = __builtin_amdgcn_mfma_f32_16x16x32_bf16(af[i], bfr[j], acc[4 + i][j], 0, 0, 0);
    __builtin_amdgcn_s_setprio(0); BARR;
    // P3: kc1, m-frags 0-3 (+ load B.k1 frags)
#pragma unroll
    for (int i = 0; i < 4; ++i) af[i] = lda(2 + par, i);
#pragma unroll
    for (int j = 0; j < 4; ++j) bfr[j] = ldb(6 + par, j);
    if (t + 2 < T) STG(W, n0, t + 2, 0, 4 + par);
    BARR; __builtin_amdgcn_s_setprio(1);
#pragma unroll
    for (int i = 0; i < 4; ++i)
#pragma unroll
      for (int j = 0; j < 4; ++j)
        acc[i][j] = __builtin_amdgcn_mfma_f32_16x16x32_bf16(af[i], bfr[j], acc[i][j], 0, 0, 0);
    __builtin_amdgcn_s_setprio(0); BARR;
    // P4: kc1, m-frags 4-7; counted vmcnt once per K-tile
#pragma unroll
    for (int i = 0; i < 4; ++i) af[i] = lda(2 + par, 4 + i);
    if (t + 2 < T) STG(A, m0, t + 2, 0, 0 + par);
    VMW;
    BARR; __builtin_amdgcn_s_setprio(1);
#pragma unroll
    for (int i = 0; i < 4; ++i)
#pragma unroll
      for (int j = 0; j < 4; ++j)
        acc[4 + i][j] = __builtin_amdgcn_mfma_f32_16x16x32_bf16(af[i], bfr[j], acc[4 + i][j], 0, 0, 0);
    __builtin_amdgcn_s_setprio(0); BARR;
  }
#undef STG
#undef BARR
#undef VMW

  const int g4 = lg << 2;
#pragma unroll
  for (int i = 0; i < 8; ++i) {
#pragma unroll
    for (int j = 0; j < 4; ++j) {
      int row0 = m0 + (wm << 7) + (i << 4) + g4;
      int col = n0 + (wn << 6) + (j << 4) + ll;
      f32x4 v = acc[i][j];
#pragma unroll
      for (int e = 0; e < 4; ++e) {
        float xx = v[e];
        out[(size_t)(row0 + e) * N + col] = f2bf(xx / (1.f + __expf(-xx)));
      }
    }
  }
}

// ---------- flash attention: swapped QK^T, lane-local softmax, XCD-local K/V ----------
__global__ __launch_bounds__(256, 2)
void attn_kernel(const u16* __restrict__ Q, const u16* __restrict__ Kg,
                 const u16* __restrict__ Vt, u16* __restrict__ Og) {
  __shared__ __align__(16) u16 Ks[128 * 64];
  __shared__ __align__(16) u16 Vs[64 * 128];
  __shared__ __align__(16) __bf16 Ps[4][16 * 128];

  const int tid = threadIdx.x;
  const int w = tid >> 6, l = tid & 63;
  const int lg = l >> 4, ll = l & 15;
  const int bid = blockIdx.x;
  const int qt = bid / 96;          // XCD-locality remap (96 % 8 == 0)
  const int bh = bid - qt * 96;
  const int b = bh / 12, hh = bh - b * 12;
  const float SC = 0.125f * 1.44269504f;  // 1/sqrt(64) * log2(e)

  bf16x8 qf[2][2];
  {
    const int tq = (b << 10) + (qt << 7) + (w << 5);
#pragma unroll
    for (int fm = 0; fm < 2; ++fm)
#pragma unroll
      for (int kc = 0; kc < 2; ++kc)
        qf[fm][kc] = *(const bf16x8*)(Q + (size_t)(tq + fm * 16 + ll) * 768 + hh * 64 + kc * 32 + lg * 8);
  }

  const f32x4 fz = {0.f, 0.f, 0.f, 0.f};
  f32x4 oacc[4][2];
#pragma unroll
  for (int i = 0; i < 4; ++i) { oacc[i][0] = fz; oacc[i][1] = fz; }
  float mrow2[2] = {-1e30f, -1e30f};
  float lrow2[2] = {0.f, 0.f};

  for (int kt = 0; kt < 8; ++kt) {
    __syncthreads();
#pragma unroll
    for (int ii = 0; ii < 4; ++ii) {
      int issue = (w << 2) + ii;
      int r = (issue << 3) + (l >> 3);
      int c = (l & 7) ^ (r & 7);
      __builtin_amdgcn_global_load_lds(
          Kg + (size_t)((b << 10) + (kt << 7) + r) * 768 + hh * 64 + c * 8,
          Ks + issue * 512, 16, 0, 0);
      int rv = (issue << 2) + (l >> 4);
      int cv = ll ^ (rv & 7);
      __builtin_amdgcn_global_load_lds(
          Vt + (size_t)((bh << 6) + rv) * 1024 + (kt << 7) + cv * 8,
          Vs + issue * 512, 16, 0, 0);
    }
    __syncthreads();

    // S^T = K Q (raw, scale folded into exp2 later via fma)
    f32x4 sa[2][8];
#pragma unroll
    for (int fm = 0; fm < 2; ++fm)
#pragma unroll
      for (int fn = 0; fn < 8; ++fn) sa[fm][fn] = fz;
    __builtin_amdgcn_s_setprio(1);
#pragma unroll
    for (int kc = 0; kc < 2; ++kc) {
      int chunk = lg + (kc << 2);
      bf16x8 kb[8];
#pragma unroll
      for (int fn = 0; fn < 8; ++fn) {
        int nr = (fn << 4) + ll;
        kb[fn] = *(const bf16x8*)((const char*)Ks + nr * 128 + ((chunk ^ (nr & 7)) << 4));
      }
#pragma unroll
      for (int fm = 0; fm < 2; ++fm)
#pragma unroll
        for (int fn = 0; fn < 8; ++fn)
          sa[fm][fn] = __builtin_amdgcn_mfma_f32_16x16x32_bf16(kb[fn], qf[fm][kc], sa[fm][fn], 0, 0, 0);
    }
    __builtin_amdgcn_s_setprio(0);

    // per-half: lane-local softmax -> Ps -> PV
#pragma unroll
    for (int fm = 0; fm < 2; ++fm) {
      f32x4 vm = sa[fm][0];
#pragma unroll
      for (int fn = 1; fn < 8; ++fn) {
#pragma unroll
        for (int e = 0; e < 4; ++e) vm[e] = fmaxf(vm[e], sa[fm][fn][e]);
      }
      float mx = fmaxf(fmaxf(vm[0], vm[1]), fmaxf(vm[2], vm[3]));
      mx = fmaxf(mx, __shfl_xor(mx, 16));
      mx = fmaxf(mx, __shfl_xor(mx, 32));
      float mnew = fmaxf(mrow2[fm], mx);
      float c2 = mnew * SC;
      float scal = __builtin_amdgcn_exp2f(__builtin_fmaf(SC, mrow2[fm], -c2));

      f32x4 vsum = fz;
#pragma unroll
      for (int fn = 0; fn < 8; ++fn) {
        f32x4 p;
#pragma unroll
        for (int e = 0; e < 4; ++e)
          p[e] = __builtin_amdgcn_exp2f(__builtin_fmaf(SC, sa[fm][fn][e], -c2));
        vsum += p;
        bf16x4 pv4;
#pragma unroll
        for (int e = 0; e < 4; ++e) pv4[e] = (__bf16)p[e];
        int chunk = (fn << 1) + (lg >> 1);
        *(bf16x4*)((char*)&Ps[w][0] + ll * 256 + ((chunk ^ (ll & 7)) << 4) + ((lg & 1) << 3)) = pv4;
      }
      float rs = (vsum[0] + vsum[1]) + (vsum[2] + vsum[3]);
      rs += __shfl_xor(rs, 16);
      rs += __shfl_xor(rs, 32);
      lrow2[fm] = lrow2[fm] * scal + rs;
      mrow2[fm] = mnew;

      asm volatile("" ::: "memory");  // order Ps writes before PV reads

#pragma unroll
      for (int fd = 0; fd < 4; ++fd) oacc[fd][fm] *= scal;

      __builtin_amdgcn_s_setprio(1);
#pragma unroll
      for (int ch = 0; ch < 4; ++ch) {
        int chunk = lg + (ch << 2);
        int qr = ll;
        bf16x8 pb = *(const bf16x8*)((const char*)&Ps[w][0] + qr * 256 + ((chunk ^ (qr & 7)) << 4));
#pragma unroll
        for (int fd = 0; fd < 4; ++fd) {
          int dr = (fd << 4) + ll;
          bf16x8 av = *(const bf16x8*)((const char*)Vs + dr * 256 + ((chunk ^ (dr & 7)) << 4));
          oacc[fd][fm] = __builtin_amdgcn_mfma_f32_16x16x32_bf16(av, pb, oacc[fd][fm], 0, 0, 0);
        }
      }
      __builtin_amdgcn_s_setprio(0);

      asm volatile("" ::: "memory");  // order PV reads before next half's Ps writes
    }
  }

  float inv0 = 1.f / lrow2[0];
  float inv1 = 1.f / lrow2[1];
  const int tq0 = (b << 10) + (qt << 7) + (w << 5);
#pragma unroll
  for (int fd = 0; fd < 4; ++fd) {
#pragma unroll
    for (int fo = 0; fo < 2; ++fo) {
      int q = (fo << 4) + ll;
      float inv = fo ? inv1 : inv0;
      f32x4 v = oacc[fd][fo];
      int d0 = (fd << 4) + (lg << 2);
      u16* o = Og + (size_t)(tq0 + q) * 768 + hh * 64 + d0;
      u32 lo = (u32)f2bf(v[0] * inv) | ((u32)f2bf(v[1] * inv) << 16);
      u32 hi = (u32)f2bf(v[2] * inv) | ((u32)f2bf(v[3] * inv) << 16);
      *(uint2*)o = make_uint2(lo, hi);
    }
  }
}

// ---------- launch ----------
extern "C" void kernel_launch(void* const* d_in, const int* in_sizes, int n_in,
                              void* d_out, int out_size, void* d_ws, size_t ws_size,
                              hipStream_t stream) {
  const float* x = (const float*)d_in[0];
  const float* wq = (const float*)d_in[1];
  const float* wk = (const float*)d_in[2];
  const float* wv = (const float*)d_in[3];
  const float* wo = (const float*)d_in[4];
  const float* w1 = (const float*)d_in[5];
  const float* w2 = (const float*)d_in[6];
  const float* anw = (const float*)d_in[7];
  const float* fnw = (const float*)d_in[8];

  char* ws = (char*)d_ws;
  float* h    = (float*)(ws);                 // 8192x768 fp32 residual stream
  u16* xn     = (u16*)(ws + 25165824);        // 8192x768 bf16
  u16* qb     = (u16*)(ws + 37748736);        // 8192x768 bf16 (Q, then attn out in-place)
  u16* kb     = (u16*)(ws + 50331648);        // 8192x768 bf16
  u16* vt     = (u16*)(ws + 62914560);        // 6144x1024 bf16 (V transposed)
  u16* ff1    = (u16*)(ws + 75497472);        // 8192x2048 bf16
  u16* wbuf   = (u16*)(ws + 109051904);       // 5505024 bf16 (per-layer weights)

  hipMemcpyAsync(h, x, 25165824, hipMemcpyDeviceToDevice, stream);

  for (int L = 0; L < 12; ++L) {
    convert_w<<<5376, 256, 0, stream>>>(
        wq + (size_t)L * 589824, wk + (size_t)L * 589824,
        wv + (size_t)L * 589824, wo + (size_t)L * 589824,
        w1 + (size_t)L * 1572864, w2 + (size_t)L * 1572864, wbuf);
    rmsnorm_k<<<2048, 256, 0, stream>>>(h, anw + L * 768, xn);
    gemm_qkv<<<1152, 256, 0, stream>>>(xn, wbuf, qb, kb, vt);
    attn_kernel<<<768, 256, 0, stream>>>(qb, kb, vt, qb);
    gemm_bt64<<<768, 256, 0, stream>>>(qb, wbuf + 1769472, h, h, 8192, 768, 768);
    rmsnorm_k<<<2048, 256, 0, stream>>>(h, fnw + L * 768, xn);
    gemm256_silu<<<256, 512, 0, stream>>>(xn, wbuf + 2359296, ff1, 8192, 2048, 768);
    float* outw = (L == 11) ? (float*)d_out : h;
    gemm_bt64<<<768, 256, 0, stream>>>(ff1, wbuf + 3932160, outw, h, 8192, 768, 2048);
  }
}

// Round 10
// 2646.349 us; speedup vs baseline: 1.0096x; 1.0096x over previous
//
#include <hip/hip_runtime.h>
#include <stdint.h>

typedef unsigned short u16;
typedef unsigned int u32;
typedef __bf16 bf16x8 __attribute__((ext_vector_type(8)));
typedef __bf16 bf16x4 __attribute__((ext_vector_type(4)));
typedef float f32x4 __attribute__((ext_vector_type(4)));

// ---------- helpers ----------
__device__ __forceinline__ u16 f2bf(float f) {
  u32 u = __builtin_bit_cast(u32, f);
  u32 r = (u + 0x7FFFu + ((u >> 16) & 1u)) >> 16;
  return (u16)r;
}

// ---------- weight fp32 -> bf16 (one layer: wq,wk,wv,wo,w1,w2 packed) ----------
__global__ __launch_bounds__(256)
void convert_w(const float* __restrict__ wq, const float* __restrict__ wk,
               const float* __restrict__ wv, const float* __restrict__ wo,
               const float* __restrict__ w1, const float* __restrict__ w2,
               u16* __restrict__ out) {
  size_t i = ((size_t)blockIdx.x * 256 + threadIdx.x) * 4;
  if (i >= 5505024) return;
  const float* src; size_t off;
  if (i < 589824)       { src = wq; off = i; }
  else if (i < 1179648) { src = wk; off = i - 589824; }
  else if (i < 1769472) { src = wv; off = i - 1179648; }
  else if (i < 2359296) { src = wo; off = i - 1769472; }
  else if (i < 3932160) { src = w1; off = i - 2359296; }
  else                  { src = w2; off = i - 3932160; }
  float4 v = *(const float4*)(src + off);
  u32 lo = (u32)f2bf(v.x) | ((u32)f2bf(v.y) << 16);
  u32 hi = (u32)f2bf(v.z) | ((u32)f2bf(v.w) << 16);
  *(uint2*)(out + i) = make_uint2(lo, hi);
}

// ---------- RMSNorm fp32 -> bf16 (D=768), one wave per token ----------
__device__ __forceinline__ void rn_store4(u16* p, float4 v, float4 w, float sc) {
  u32 lo = (u32)f2bf(v.x * sc * w.x) | ((u32)f2bf(v.y * sc * w.y) << 16);
  u32 hi = (u32)f2bf(v.z * sc * w.z) | ((u32)f2bf(v.w * sc * w.w) << 16);
  *(uint2*)p = make_uint2(lo, hi);
}

__global__ __launch_bounds__(256)
void rmsnorm_k(const float* __restrict__ x, const float* __restrict__ w,
               u16* __restrict__ out) {
  const int tok = (blockIdx.x << 2) + (threadIdx.x >> 6);
  const int l = threadIdx.x & 63;
  const float* xr = x + (size_t)tok * 768;
  float4 v0 = *(const float4*)(xr + l * 4);
  float4 v1 = *(const float4*)(xr + 256 + l * 4);
  float4 v2 = *(const float4*)(xr + 512 + l * 4);
  float ss = v0.x*v0.x + v0.y*v0.y + v0.z*v0.z + v0.w*v0.w
           + v1.x*v1.x + v1.y*v1.y + v1.z*v1.z + v1.w*v1.w
           + v2.x*v2.x + v2.y*v2.y + v2.z*v2.z + v2.w*v2.w;
  ss += __shfl_xor(ss, 1);  ss += __shfl_xor(ss, 2);  ss += __shfl_xor(ss, 4);
  ss += __shfl_xor(ss, 8);  ss += __shfl_xor(ss, 16); ss += __shfl_xor(ss, 32);
  float sc = rsqrtf(ss * (1.f / 768.f) + 1e-12f);
  float4 w0 = *(const float4*)(w + l * 4);
  float4 w1v = *(const float4*)(w + 256 + l * 4);
  float4 w2v = *(const float4*)(w + 512 + l * 4);
  u16* o = out + (size_t)tok * 768;
  rn_store4(o + l * 4, v0, w0, sc);
  rn_store4(o + 256 + l * 4, v1, w1v, sc);
  rn_store4(o + 512 + l * 4, v2, w2v, sc);
}

// ---------- GEMM core staging+compute (128x128 tile, 4 waves, m97 structure) ----------
#define GEMM_CORE(A_, W_, K_, m0_, n0_)                                             \
  for (int kt = 0; kt < (K_); kt += 64) {                                           \
    __syncthreads();                                                                \
    _Pragma("unroll")                                                               \
    for (int ii = 0; ii < 4; ++ii) {                                                \
      int issue = (w << 2) + ii;                                                    \
      int r = (issue << 3) + (l >> 3);                                              \
      int c = (l & 7) ^ (r & 7);                                                    \
      __builtin_amdgcn_global_load_lds((A_) + (size_t)((m0_) + r) * (K_) + kt + c * 8, \
                                       As + issue * 512, 16, 0, 0);                 \
      __builtin_amdgcn_global_load_lds((W_) + (size_t)((n0_) + r) * (K_) + kt + c * 8, \
                                       Ws + issue * 512, 16, 0, 0);                 \
    }                                                                               \
    __syncthreads();                                                                \
    _Pragma("unroll")                                                               \
    for (int kc = 0; kc < 2; ++kc) {                                                \
      int chunk = lg + (kc << 2);                                                   \
      bf16x8 af[4], bfr[4];                                                         \
      _Pragma("unroll")                                                             \
      for (int i = 0; i < 4; ++i) {                                                 \
        int mr = (wm << 6) + (i << 4) + ll;                                         \
        af[i] = *(const bf16x8*)((const char*)As + mr * 128 + ((chunk ^ (mr & 7)) << 4)); \
        int nr = (wn << 6) + (i << 4) + ll;                                         \
        bfr[i] = *(const bf16x8*)((const char*)Ws + nr * 128 + ((chunk ^ (nr & 7)) << 4)); \
      }                                                                             \
      _Pragma("unroll")                                                             \
      for (int i = 0; i < 4; ++i)                                                   \
        _Pragma("unroll")                                                           \
        for (int j = 0; j < 4; ++j)                                                 \
          acc[i][j] = __builtin_amdgcn_mfma_f32_16x16x32_bf16(af[i], bfr[j], acc[i][j], 0, 0, 0); \
    }                                                                               \
  }

// ---------- generic BT GEMM: C[M][N] = A[M][K](bf16) * W[N][K](bf16) ----------
// EP: 0 = bf16 store; 1 = fp32 residual; 2 = silu -> bf16
template<int EP>
__global__ __launch_bounds__(256, 2)
void gemm_bt(const u16* __restrict__ A, const u16* __restrict__ W,
             void* __restrict__ outp, const float* __restrict__ Res,
             int M, int N, int K) {
  __shared__ __align__(16) u16 As[128 * 64];
  __shared__ __align__(16) u16 Ws[128 * 64];
  const int tid = threadIdx.x;
  const int w = tid >> 6, l = tid & 63;
  const int lg = l >> 4, ll = l & 15;
  const int ntiles = N >> 7;
  const int mt = blockIdx.x / ntiles, nt = blockIdx.x - mt * ntiles;
  const int m0 = mt << 7, n0 = nt << 7;
  const int wm = w >> 1, wn = w & 1;

  const f32x4 fz = {0.f, 0.f, 0.f, 0.f};
  f32x4 acc[4][4];
#pragma unroll
  for (int i = 0; i < 4; ++i)
#pragma unroll
    for (int j = 0; j < 4; ++j) acc[i][j] = fz;

  GEMM_CORE(A, W, K, m0, n0)

  const int g4 = lg << 2;
#pragma unroll
  for (int i = 0; i < 4; ++i) {
#pragma unroll
    for (int j = 0; j < 4; ++j) {
      int row0 = m0 + (wm << 6) + (i << 4) + g4;
      int col = n0 + (wn << 6) + (j << 4) + ll;
      f32x4 v = acc[i][j];
      if (EP == 0) {
        u16* o = (u16*)outp;
#pragma unroll
        for (int e = 0; e < 4; ++e) o[(size_t)(row0 + e) * N + col] = f2bf(v[e]);
      } else if (EP == 1) {
        float* o = (float*)outp;
#pragma unroll
        for (int e = 0; e < 4; ++e) {
          size_t idx = (size_t)(row0 + e) * N + col;
          o[idx] = Res[idx] + v[e];
        }
      } else {
        u16* o = (u16*)outp;
#pragma unroll
        for (int e = 0; e < 4; ++e) {
          float xx = v[e];
          o[(size_t)(row0 + e) * N + col] = f2bf(xx / (1.f + __expf(-xx)));
        }
      }
    }
  }
}

// ---------- 64x128-tile BT GEMM, fp32-residual epilogue (wo / ffn2) ----------
__global__ __launch_bounds__(256, 4)
void gemm_bt64(const u16* __restrict__ A, const u16* __restrict__ W,
               float* __restrict__ outp, const float* __restrict__ Res,
               int M, int N, int K) {
  __shared__ __align__(16) u16 As[64 * 64];
  __shared__ __align__(16) u16 Ws[128 * 64];
  const int tid = threadIdx.x;
  const int w = tid >> 6, l = tid & 63;
  const int lg = l >> 4, ll = l & 15;
  const int ntiles = N >> 7;
  const int mt = blockIdx.x / ntiles, nt = blockIdx.x - mt * ntiles;
  const int m0 = mt << 6, n0 = nt << 7;
  const int wm = w >> 1, wn = w & 1;

  const f32x4 fz = {0.f, 0.f, 0.f, 0.f};
  f32x4 acc[2][4];
#pragma unroll
  for (int i = 0; i < 2; ++i)
#pragma unroll
    for (int j = 0; j < 4; ++j) acc[i][j] = fz;

  for (int kt = 0; kt < K; kt += 64) {
    __syncthreads();
#pragma unroll
    for (int ii = 0; ii < 6; ++ii) {
      int issue = w * 6 + ii;  // 0..23, wave-uniform
      if (issue < 8) {
        int r = (issue << 3) + (l >> 3);
        int c = (l & 7) ^ (r & 7);
        __builtin_amdgcn_global_load_lds(A + (size_t)(m0 + r) * K + kt + c * 8,
                                         As + issue * 512, 16, 0, 0);
      } else {
        int is2 = issue - 8;
        int r = (is2 << 3) + (l >> 3);
        int c = (l & 7) ^ (r & 7);
        __builtin_amdgcn_global_load_lds(W + (size_t)(n0 + r) * K + kt + c * 8,
                                         Ws + is2 * 512, 16, 0, 0);
      }
    }
    __syncthreads();
#pragma unroll
    for (int kc = 0; kc < 2; ++kc) {
      int chunk = lg + (kc << 2);
      bf16x8 af[2], bfr[4];
#pragma unroll
      for (int i = 0; i < 2; ++i) {
        int mr = (wm << 5) + (i << 4) + ll;
        af[i] = *(const bf16x8*)((const char*)As + mr * 128 + ((chunk ^ (mr & 7)) << 4));
      }
#pragma unroll
      for (int j = 0; j < 4; ++j) {
        int nr = (wn << 6) + (j << 4) + ll;
        bfr[j] = *(const bf16x8*)((const char*)Ws + nr * 128 + ((chunk ^ (nr & 7)) << 4));
      }
#pragma unroll
      for (int i = 0; i < 2; ++i)
#pragma unroll
        for (int j = 0; j < 4; ++j)
          acc[i][j] = __builtin_amdgcn_mfma_f32_16x16x32_bf16(af[i], bfr[j], acc[i][j], 0, 0, 0);
    }
  }

  const int g4 = lg << 2;
#pragma unroll
  for (int i = 0; i < 2; ++i) {
#pragma unroll
    for (int j = 0; j < 4; ++j) {
      int row0 = m0 + (wm << 5) + (i << 4) + g4;
      int col = n0 + (wn << 6) + (j << 4) + ll;
      f32x4 v = acc[i][j];
#pragma unroll
      for (int e = 0; e < 4; ++e) {
        size_t idx = (size_t)(row0 + e) * N + col;
        outp[idx] = Res[idx] + v[e];
      }
    }
  }
}

// ---------- fused QKV GEMM: A[8192][768] x Wqkv[2304][768]; routes per n-tile ----------
__global__ __launch_bounds__(256, 2)
void gemm_qkv(const u16* __restrict__ A, const u16* __restrict__ W,
              u16* __restrict__ Qo, u16* __restrict__ Ko, u16* __restrict__ Vo) {
  __shared__ __align__(16) u16 As[128 * 64];
  __shared__ __align__(16) u16 Ws[128 * 64];
  const int tid = threadIdx.x;
  const int w = tid >> 6, l = tid & 63;
  const int lg = l >> 4, ll = l & 15;
  const int mt = blockIdx.x / 18, nt = blockIdx.x - mt * 18;
  const int m0 = mt << 7, n0 = nt << 7;
  const int wm = w >> 1, wn = w & 1;
  const int K = 768;

  const f32x4 fz = {0.f, 0.f, 0.f, 0.f};
  f32x4 acc[4][4];
#pragma unroll
  for (int i = 0; i < 4; ++i)
#pragma unroll
    for (int j = 0; j < 4; ++j) acc[i][j] = fz;

  GEMM_CORE(A, W, K, m0, n0)

  const int g4 = lg << 2;
#pragma unroll
  for (int i = 0; i < 4; ++i) {
#pragma unroll
    for (int j = 0; j < 4; ++j) {
      int row0 = m0 + (wm << 6) + (i << 4) + g4;
      int col = n0 + (wn << 6) + (j << 4) + ll;
      f32x4 v = acc[i][j];
      if (nt < 12) {
        u16* o = (nt < 6) ? Qo : Ko;
        int c = (nt < 6) ? col : (col - 768);
#pragma unroll
        for (int e = 0; e < 4; ++e) o[(size_t)(row0 + e) * 768 + c] = f2bf(v[e]);
      } else {
        int c = col - 1536;
        int vrow = ((row0 >> 10) * 768) + c;
        u32 lo = (u32)f2bf(v[0]) | ((u32)f2bf(v[1]) << 16);
        u32 hi = (u32)f2bf(v[2]) | ((u32)f2bf(v[3]) << 16);
        *(uint2*)(Vo + ((size_t)vrow << 10) + (row0 & 1023)) = make_uint2(lo, hi);
      }
    }
  }
}

// ---------- flash attention: swapped QK^T, lane-local softmax, XCD-local K/V, ----------
// ---------- T14 reg-staged K/V prefetch (issue-early / ds_write-late)         ----------
__global__ __launch_bounds__(256, 2)
void attn_kernel(const u16* __restrict__ Q, const u16* __restrict__ Kg,
                 const u16* __restrict__ Vt, u16* __restrict__ Og) {
  __shared__ __align__(16) __bf16 Ks[128 * 64];    // [key 128][dim 64], XOR-swizzled
  __shared__ __align__(16) __bf16 Vs[64 * 128];    // [dim 64][key 128], XOR-swizzled
  __shared__ __align__(16) __bf16 Ps[4][16 * 128]; // per-wave P half, XOR-swizzled

  const int tid = threadIdx.x;
  const int w = tid >> 6, l = tid & 63;
  const int lg = l >> 4, ll = l & 15;
  const int bid = blockIdx.x;
  const int qt = bid / 96;          // XCD-locality remap (96 % 8 == 0)
  const int bh = bid - qt * 96;
  const int b = bh / 12, hh = bh - b * 12;
  const float SC = 0.125f * 1.44269504f;  // 1/sqrt(64) * log2(e)

  bf16x8 qf[2][2];
  {
    const int tq = (b << 10) + (qt << 7) + (w << 5);
#pragma unroll
    for (int fm = 0; fm < 2; ++fm)
#pragma unroll
      for (int kc = 0; kc < 2; ++kc)
        qf[fm][kc] = *(const bf16x8*)(Q + (size_t)(tq + fm * 16 + ll) * 768 + hh * 64 + kc * 32 + lg * 8);
  }

  // K/V prefetch registers (4 + 4 x bf16x8 = 32 VGPR)
  bf16x8 kp[4], vp[4];
#define ISSUE_KV(t_)                                                                  \
  { _Pragma("unroll")                                                                 \
    for (int ii = 0; ii < 4; ++ii) {                                                  \
      int issue = (w << 2) + ii;                                                      \
      int r = (issue << 3) + (l >> 3);                                                \
      int c = (l & 7) ^ (r & 7);                                                      \
      kp[ii] = *(const bf16x8*)(Kg + (size_t)((b << 10) + ((t_) << 7) + r) * 768 + hh * 64 + c * 8); \
      int rv = (issue << 2) + (l >> 4);                                               \
      int cv = ll ^ (rv & 7);                                                         \
      vp[ii] = *(const bf16x8*)(Vt + (size_t)((bh << 6) + rv) * 1024 + ((t_) << 7) + cv * 8); \
    } }
#define WRITE_KV                                                                      \
  { _Pragma("unroll")                                                                 \
    for (int ii = 0; ii < 4; ++ii) {                                                  \
      int issue = (w << 2) + ii;                                                      \
      *(bf16x8*)((char*)Ks + issue * 1024 + l * 16) = kp[ii];                         \
      *(bf16x8*)((char*)Vs + issue * 1024 + l * 16) = vp[ii];                         \
    } }

  const f32x4 fz = {0.f, 0.f, 0.f, 0.f};
  f32x4 oacc[4][2];
#pragma unroll
  for (int i = 0; i < 4; ++i) { oacc[i][0] = fz; oacc[i][1] = fz; }
  float mrow2[2] = {-1e30f, -1e30f};
  float lrow2[2] = {0.f, 0.f};

  ISSUE_KV(0);
  WRITE_KV;
  __syncthreads();

  for (int kt = 0; kt < 8; ++kt) {
    // issue next tile's loads early; latency hides under this tile's compute
    if (kt < 7) ISSUE_KV(kt + 1);

    // S^T = K Q (raw, scale folded into exp2 later via fma)
    f32x4 sa[2][8];
#pragma unroll
    for (int fm = 0; fm < 2; ++fm)
#pragma unroll
      for (int fn = 0; fn < 8; ++fn) sa[fm][fn] = fz;
    __builtin_amdgcn_s_setprio(1);
#pragma unroll
    for (int kc = 0; kc < 2; ++kc) {
      int chunk = lg + (kc << 2);
      bf16x8 kb[8];
#pragma unroll
      for (int fn = 0; fn < 8; ++fn) {
        int nr = (fn << 4) + ll;
        kb[fn] = *(const bf16x8*)((const char*)Ks + nr * 128 + ((chunk ^ (nr & 7)) << 4));
      }
#pragma unroll
      for (int fm = 0; fm < 2; ++fm)
#pragma unroll
        for (int fn = 0; fn < 8; ++fn)
          sa[fm][fn] = __builtin_amdgcn_mfma_f32_16x16x32_bf16(kb[fn], qf[fm][kc], sa[fm][fn], 0, 0, 0);
    }
    __builtin_amdgcn_s_setprio(0);

    // per-half: lane-local softmax -> Ps -> PV
#pragma unroll
    for (int fm = 0; fm < 2; ++fm) {
      f32x4 vm = sa[fm][0];
#pragma unroll
      for (int fn = 1; fn < 8; ++fn) {
#pragma unroll
        for (int e = 0; e < 4; ++e) vm[e] = fmaxf(vm[e], sa[fm][fn][e]);
      }
      float mx = fmaxf(fmaxf(vm[0], vm[1]), fmaxf(vm[2], vm[3]));
      mx = fmaxf(mx, __shfl_xor(mx, 16));
      mx = fmaxf(mx, __shfl_xor(mx, 32));
      float mnew = fmaxf(mrow2[fm], mx);
      float c2 = mnew * SC;
      float scal = __builtin_amdgcn_exp2f(__builtin_fmaf(SC, mrow2[fm], -c2));

      f32x4 vsum = fz;
#pragma unroll
      for (int fn = 0; fn < 8; ++fn) {
        f32x4 p;
#pragma unroll
        for (int e = 0; e < 4; ++e)
          p[e] = __builtin_amdgcn_exp2f(__builtin_fmaf(SC, sa[fm][fn][e], -c2));
        vsum += p;
        bf16x4 pv4;
#pragma unroll
        for (int e = 0; e < 4; ++e) pv4[e] = (__bf16)p[e];
        int chunk = (fn << 1) + (lg >> 1);
        *(bf16x4*)((char*)&Ps[w][0] + ll * 256 + ((chunk ^ (ll & 7)) << 4) + ((lg & 1) << 3)) = pv4;
      }
      float rs = (vsum[0] + vsum[1]) + (vsum[2] + vsum[3]);
      rs += __shfl_xor(rs, 16);
      rs += __shfl_xor(rs, 32);
      lrow2[fm] = lrow2[fm] * scal + rs;
      mrow2[fm] = mnew;

      asm volatile("" ::: "memory");  // order Ps writes before PV reads

#pragma unroll
      for (int fd = 0; fd < 4; ++fd) oacc[fd][fm] *= scal;

      __builtin_amdgcn_s_setprio(1);
#pragma unroll
      for (int ch = 0; ch < 4; ++ch) {
        int chunk = lg + (ch << 2);
        int qr = ll;
        bf16x8 pb = *(const bf16x8*)((const char*)&Ps[w][0] + qr * 256 + ((chunk ^ (qr & 7)) << 4));
#pragma unroll
        for (int fd = 0; fd < 4; ++fd) {
          int dr = (fd << 4) + ll;
          bf16x8 av = *(const bf16x8*)((const char*)Vs + dr * 256 + ((chunk ^ (dr & 7)) << 4));
          oacc[fd][fm] = __builtin_amdgcn_mfma_f32_16x16x32_bf16(av, pb, oacc[fd][fm], 0, 0, 0);
        }
      }
      __builtin_amdgcn_s_setprio(0);

      asm volatile("" ::: "memory");  // order PV reads before next half's Ps writes
    }

    // write-late: all waves done reading Ks/Vs -> overwrite with prefetched tile
    if (kt < 7) {
      __syncthreads();
      WRITE_KV;
      __syncthreads();
    }
  }
#undef ISSUE_KV
#undef WRITE_KV

  float inv0 = 1.f / lrow2[0];
  float inv1 = 1.f / lrow2[1];
  const int tq0 = (b << 10) + (qt << 7) + (w << 5);
#pragma unroll
  for (int fd = 0; fd < 4; ++fd) {
#pragma unroll
    for (int fo = 0; fo < 2; ++fo) {
      int q = (fo << 4) + ll;
      float inv = fo ? inv1 : inv0;
      f32x4 v = oacc[fd][fo];
      int d0 = (fd << 4) + (lg << 2);
      u16* o = Og + (size_t)(tq0 + q) * 768 + hh * 64 + d0;
      u32 lo = (u32)f2bf(v[0] * inv) | ((u32)f2bf(v[1] * inv) << 16);
      u32 hi = (u32)f2bf(v[2] * inv) | ((u32)f2bf(v[3] * inv) << 16);
      *(uint2*)o = make_uint2(lo, hi);
    }
  }
}

// ---------- launch ----------
extern "C" void kernel_launch(void* const* d_in, const int* in_sizes, int n_in,
                              void* d_out, int out_size, void* d_ws, size_t ws_size,
                              hipStream_t stream) {
  const float* x = (const float*)d_in[0];
  const float* wq = (const float*)d_in[1];
  const float* wk = (const float*)d_in[2];
  const float* wv = (const float*)d_in[3];
  const float* wo = (const float*)d_in[4];
  const float* w1 = (const float*)d_in[5];
  const float* w2 = (const float*)d_in[6];
  const float* anw = (const float*)d_in[7];
  const float* fnw = (const float*)d_in[8];

  char* ws = (char*)d_ws;
  float* h    = (float*)(ws);                 // 8192x768 fp32 residual stream
  u16* xn     = (u16*)(ws + 25165824);        // 8192x768 bf16
  u16* qb     = (u16*)(ws + 37748736);        // 8192x768 bf16 (Q, then attn out in-place)
  u16* kb     = (u16*)(ws + 50331648);        // 8192x768 bf16
  u16* vt     = (u16*)(ws + 62914560);        // 6144x1024 bf16 (V transposed)
  u16* ff1    = (u16*)(ws + 75497472);        // 8192x2048 bf16
  u16* wbuf   = (u16*)(ws + 109051904);       // 5505024 bf16 (per-layer weights)

  hipMemcpyAsync(h, x, 25165824, hipMemcpyDeviceToDevice, stream);

  for (int L = 0; L < 12; ++L) {
    convert_w<<<5376, 256, 0, stream>>>(
        wq + (size_t)L * 589824, wk + (size_t)L * 589824,
        wv + (size_t)L * 589824, wo + (size_t)L * 589824,
        w1 + (size_t)L * 1572864, w2 + (size_t)L * 1572864, wbuf);
    rmsnorm_k<<<2048, 256, 0, stream>>>(h, anw + L * 768, xn);
    gemm_qkv<<<1152, 256, 0, stream>>>(xn, wbuf, qb, kb, vt);
    attn_kernel<<<768, 256, 0, stream>>>(qb, kb, vt, qb);
    gemm_bt64<<<768, 256, 0, stream>>>(qb, wbuf + 1769472, h, h, 8192, 768, 768);
    rmsnorm_k<<<2048, 256, 0, stream>>>(h, fnw + L * 768, xn);
    gemm_bt<2><<<1024, 256, 0, stream>>>(xn, wbuf + 2359296, ff1, nullptr, 8192, 2048, 768);
    float* outw = (L == 11) ? (float*)d_out : h;
    gemm_bt64<<<768, 256, 0, stream>>>(ff1, wbuf + 3932160, outw, h, 8192, 768, 2048);
  }
}